// Round 1
// 689.839 us; speedup vs baseline: 1.5212x; 1.5212x over previous
//
#include <hip/hip_runtime.h>
#include <hip/hip_bf16.h>

#define Bv 4096
#define Dv 512
#define Nv 10000

#define BM 128
#define BK 32

typedef __attribute__((ext_vector_type(8))) short short8;
typedef __attribute__((ext_vector_type(4))) float f32x4;

__device__ __forceinline__ unsigned short f2bf(float x) {
  union { __hip_bfloat16 h; unsigned short u; } v;
  v.h = __float2bfloat16(x);
  return v.u;
}

// async global->LDS, 16B per lane. LDS dest is wave-uniform base + lane*16;
// callers must arrange lane l's lds ptr == base + l*16 (we do).
__device__ __forceinline__ void gload16(const void* g, void* l) {
  __builtin_amdgcn_global_load_lds(
      (const __attribute__((address_space(1))) void*)g,
      (__attribute__((address_space(3))) void*)l,
      16, 0, 0);
}

// ---------------- kernel 0: counting sort of data_indx ----------------
// The whole loss is invariant under a simultaneous permutation of the batch
// dim (rows and cols permuted identically, Y/s permuted to match). Sorting
// makes each 128-col gather tile a CONTIGUOUS ~312-value window of the ML/CL
// rows: fetch/row-visit drops ~7.2KB -> ~1.3KB (5.3x less HBM traffic).
__global__ __launch_bounds__(1024) void sort_kernel(
    const int* __restrict__ idx, int* __restrict__ sidx,
    int* __restrict__ perm)
{
  __shared__ unsigned int bins[10240];  // 10000 bins, padded to 1024*10
  __shared__ unsigned int tsum[1024];
  const int t = threadIdx.x;
  for (int i = t; i < 10240; i += 1024) bins[i] = 0u;
  __syncthreads();
  const int v0 = idx[t], v1 = idx[t + 1024];
  const int v2 = idx[t + 2048], v3 = idx[t + 3072];
  atomicAdd(&bins[v0], 1u); atomicAdd(&bins[v1], 1u);
  atomicAdd(&bins[v2], 1u); atomicAdd(&bins[v3], 1u);
  __syncthreads();
  // per-thread chunk of 10 bins -> chunk total
  const int base = t * 10;
  unsigned int s = 0;
  #pragma unroll
  for (int i = 0; i < 10; ++i) s += bins[base + i];
  tsum[t] = s;
  __syncthreads();
  // Hillis-Steele inclusive scan over the 1024 chunk totals
  for (int off = 1; off < 1024; off <<= 1) {
    const unsigned int x = (t >= off) ? tsum[t - off] : 0u;
    __syncthreads();
    tsum[t] += x;
    __syncthreads();
  }
  // rewrite own chunk: counts -> exclusive start offsets
  unsigned int run = (t > 0) ? tsum[t - 1] : 0u;
  #pragma unroll
  for (int i = 0; i < 10; ++i) {
    const unsigned int c = bins[base + i];
    bins[base + i] = run;
    run += c;
  }
  __syncthreads();
  // scatter (order within equal keys irrelevant)
  unsigned int d;
  d = atomicAdd(&bins[v0], 1u); sidx[d] = v0; perm[d] = t;
  d = atomicAdd(&bins[v1], 1u); sidx[d] = v1; perm[d] = t + 1024;
  d = atomicAdd(&bins[v2], 1u); sidx[d] = v2; perm[d] = t + 2048;
  d = atomicAdd(&bins[v3], 1u); sidx[d] = v3; perm[d] = t + 3072;
}

// ------- kernel 1: permuted bf16 cast + s_i + mse partials -------
// Row `row` of the permuted problem is source row perm[row]; ybf/s come out
// already in sorted order so gram_fused needs no changes.
__global__ __launch_bounds__(128) void prep_kernel(
    const float* __restrict__ yp, const float* __restrict__ yt,
    const int* __restrict__ perm, unsigned short* __restrict__ ybf,
    float* __restrict__ s_out, float* __restrict__ msep)
{
  const int row = blockIdx.x;   // 4096 rows (permuted order)
  const int src = perm[row];
  const int t = threadIdx.x;    // 128 threads, 1 float4 each (D=512)
  const float4* yp4 = (const float4*)(yp + (size_t)src * Dv);
  const float4* yt4 = (const float4*)(yt + (size_t)src * Dv);
  float4 a = yp4[t];
  float4 b = yt4[t];
  uint2 pk;
  pk.x = (unsigned int)f2bf(a.x) | ((unsigned int)f2bf(a.y) << 16);
  pk.y = (unsigned int)f2bf(a.z) | ((unsigned int)f2bf(a.w) << 16);
  *(uint2*)(ybf + (size_t)row * Dv + t * 4) = pk;

  float ss = a.x*a.x + a.y*a.y + a.z*a.z + a.w*a.w;
  float dx = a.x-b.x, dy = a.y-b.y, dz = a.z-b.z, dw = a.w-b.w;
  float dd = dx*dx + dy*dy + dz*dz + dw*dw;
  #pragma unroll
  for (int off = 32; off; off >>= 1) {
    ss += __shfl_down(ss, off);
    dd += __shfl_down(dd, off);
  }
  __shared__ float r0[2], r1[2];
  if ((t & 63) == 0) { r0[t >> 6] = ss; r1[t >> 6] = dd; }
  __syncthreads();
  if (t == 0) { s_out[row] = r0[0] + r0[1]; msep[row] = r1[0] + r1[1]; }
}

// ------------- kernel 2: fused Gram-tile GEMM + gather-reduce -------------
// grid = 32*32 blocks, one 128x128 tile of G = Y Y^T each; 256 threads.
// indx is now SORTED: each col tile's gather spans a contiguous ~312-row
// window of ML/CL -> dense line utilization.
__global__ __launch_bounds__(256) void gram_fused(
    const unsigned short* __restrict__ Ybf, const int* __restrict__ indx,
    const float* __restrict__ s_in, const float* __restrict__ ML,
    const float* __restrict__ CL, float* __restrict__ partML,
    float* __restrict__ partCL)
{
  alignas(16) __shared__ unsigned short At[BM * BK]; // [row][k], 8KB
  alignas(16) __shared__ unsigned short Bt[BM * BK]; // [col][k], 8KB
  __shared__ int sIdxI[BM];
  __shared__ int sIdxJ[BM];
  __shared__ float sS[BM];
  __shared__ float redML[4], redCL[4];

  const int bx = blockIdx.x;
  const int ti = bx >> 5, tj = bx & 31;
  const int i0 = ti * BM, j0 = tj * BM;
  const int tid = threadIdx.x;
  const int lane = tid & 63, w = tid >> 6;

  if (tid < BM) {
    sIdxI[tid] = indx[i0 + tid];
    sS[tid]    = s_in[i0 + tid];
  } else {
    sIdxJ[tid - BM] = indx[j0 + (tid - BM)];
  }

  f32x4 acc[4][4];
  #pragma unroll
  for (int a = 0; a < 4; ++a)
    #pragma unroll
    for (int b = 0; b < 4; ++b)
      acc[a][b] = (f32x4){0.f, 0.f, 0.f, 0.f};

  const int wrow = (w >> 1) * 64;   // wave's 64x64 region in the 128x128 tile
  const int wcol = (w & 1) * 64;
  const int frow = lane & 15;       // fragment row/col within 16x16
  const int fq   = lane >> 4;       // quad 0..3

  for (int kt = 0; kt < Dv / BK; ++kt) {
    const int k0 = kt * BK;
    // stage A (rows i0..) and B (rows j0..) tiles: 512 16B-chunks each,
    // chunk c -> row c>>2, k-offset (c&3)*8; lds offset c*16B (lane-contig).
    #pragma unroll
    for (int p = 0; p < 2; ++p) {
      const int c = tid + p * 256;
      const int r = c >> 2, kc = (c & 3) * 8;
      gload16(Ybf + (size_t)(i0 + r) * Dv + k0 + kc, &At[c * 8]);
      gload16(Ybf + (size_t)(j0 + r) * Dv + k0 + kc, &Bt[c * 8]);
    }
    __syncthreads();   // compiler drains vmcnt before s_barrier

    short8 af[4], bf[4];
    #pragma unroll
    for (int mt = 0; mt < 4; ++mt)
      af[mt] = *(const short8*)&At[(wrow + mt * 16 + frow) * BK + fq * 8];
    #pragma unroll
    for (int nt = 0; nt < 4; ++nt)
      bf[nt] = *(const short8*)&Bt[(wcol + nt * 16 + frow) * BK + fq * 8];

    #pragma unroll
    for (int mt = 0; mt < 4; ++mt)
      #pragma unroll
      for (int nt = 0; nt < 4; ++nt)
        acc[mt][nt] = __builtin_amdgcn_mfma_f32_16x16x32_bf16(
            af[mt], bf[nt], acc[mt][nt], 0, 0, 0);
    __syncthreads();
  }

  // epilogue: C/D layout col = lane&15, row = (lane>>4)*4 + reg (m89/m91)
  float tml = 0.f, tcl = 0.f;
  #pragma unroll
  for (int mt = 0; mt < 4; ++mt) {
    const int giB = wrow + mt * 16 + fq * 4;
    size_t rb[4]; float sv[4];
    #pragma unroll
    for (int r = 0; r < 4; ++r) {
      rb[r] = (size_t)sIdxI[giB + r] * Nv;
      sv[r] = sS[giB + r];
    }
    #pragma unroll
    for (int nt = 0; nt < 4; ++nt) {
      const int rj = sIdxJ[wcol + nt * 16 + frow];
      #pragma unroll
      for (int r = 0; r < 4; ++r) {
        const float d = sv[r] - acc[mt][nt][r];
        tml += ML[rb[r] + rj] * d;
        tcl += CL[rb[r] + rj] * d;
      }
    }
  }
  #pragma unroll
  for (int off = 32; off; off >>= 1) {
    tml += __shfl_down(tml, off);
    tcl += __shfl_down(tcl, off);
  }
  if (lane == 0) { redML[w] = tml; redCL[w] = tcl; }
  __syncthreads();
  if (tid == 0) {
    partML[bx] = redML[0] + redML[1] + redML[2] + redML[3];
    partCL[bx] = redCL[0] + redCL[1] + redCL[2] + redCL[3];
  }
}

// ---------------- kernel 3: final reduce + scalar outputs ----------------
__global__ __launch_bounds__(256) void final_kernel(
    const float* __restrict__ msep, const float* __restrict__ partML,
    const float* __restrict__ partCL, float* __restrict__ out)
{
  const int t = threadIdx.x;
  float m = 0.f, a = 0.f, c = 0.f;
  for (int i = t; i < Bv; i += 256) m += msep[i];
  for (int i = t; i < 1024; i += 256) { a += partML[i]; c += partCL[i]; }
  #pragma unroll
  for (int off = 32; off; off >>= 1) {
    m += __shfl_down(m, off);
    a += __shfl_down(a, off);
    c += __shfl_down(c, off);
  }
  __shared__ float rm[4], ra[4], rc[4];
  const int w = t >> 6;
  if ((t & 63) == 0) { rm[w] = m; ra[w] = a; rc[w] = c; }
  __syncthreads();
  if (t == 0) {
    const float mse = (rm[0] + rm[1] + rm[2] + rm[3]) /
                      ((float)Bv * (float)Dv);
    const float sc  = 2.0f / ((float)Bv * (float)Bv);
    const float lml = (ra[0] + ra[1] + ra[2] + ra[3]) * sc;
    const float lcl = (rc[0] + rc[1] + rc[2] + rc[3]) * sc;
    out[0] = mse + 0.5f * lml - 0.5f * lcl;  // GAMMA=0.5, ALPHA=0.5
    out[1] = lml;
    out[2] = lcl;
  }
}

extern "C" void kernel_launch(void* const* d_in, const int* in_sizes, int n_in,
                              void* d_out, int out_size, void* d_ws, size_t ws_size,
                              hipStream_t stream) {
  const float* yp   = (const float*)d_in[0];
  const float* yt   = (const float*)d_in[1];
  const int*   idx  = (const int*)d_in[2];
  const float* ML   = (const float*)d_in[3];
  const float* CL   = (const float*)d_in[4];
  float* out = (float*)d_out;

  // workspace layout: [0,4MB) ybf ; then s[4096], msep[4096], partML[1024],
  // partCL[1024], sidx[4096], perm[4096]  -> ~4.31MB total
  unsigned short* ybf = (unsigned short*)d_ws;
  float* s_buf = (float*)((char*)d_ws + (4u << 20));
  float* msep  = s_buf + Bv;
  float* pml   = msep + Bv;
  float* pcl   = pml + 1024;
  int*   sidx  = (int*)(pcl + 1024);
  int*   perm  = sidx + Bv;

  sort_kernel<<<1, 1024, 0, stream>>>(idx, sidx, perm);
  prep_kernel<<<Bv, 128, 0, stream>>>(yp, yt, perm, ybf, s_buf, msep);
  gram_fused<<<32 * 32, 256, 0, stream>>>(ybf, sidx, s_buf, ML, CL, pml, pcl);
  final_kernel<<<1, 256, 0, stream>>>(msep, pml, pcl, out);
}